// Round 3
// baseline (171.534 us; speedup 1.0000x reference)
//
#include <hip/hip_runtime.h>

#define HW_   5776                  // 76*76
#define W_    76
#define NPOS  (16 * 3 * HW_)        // 277248 positions total
#define TPS   46                    // tiles per slab: 45 full + 1 overlapped tail
#define NWG   (48 * TPS)            // 2208 blocks, % 8 == 0
#define ROWQ  24                    // float4 slots per out-stage row (20 + xor pad)

typedef float f32x4_ __attribute__((ext_vector_type(4)));

__device__ __forceinline__ float sigmoidf_(float x) {
    return 1.0f / (1.0f + __expf(-x));
}

__device__ __forceinline__ void nt_store4(const float4& v, float4* p) {
    __builtin_nontemporal_store(*(const f32x4_*)&v, (f32x4_*)p);
}

// Block = 128 positions of ONE slab (b*3+a). Input staged via cooperative
// float4 loads (1 KB / wave-instruction, 2 x 512 B segments) into an LDS
// [85][128] transpose buffer; per-position softmax runs on adjacent-lane
// pairs (40 classes each). Output conf re-uses the same LDS (aliased, two
// barriers) with the proven xor-swizzled stage + per-wave coalesced drain.
// vmem instructions per wave drop 56 -> 22 while every global access is
// >= 512 B contiguous per segment. Outputs use nontemporal stores so the
// output stream does not evict the input from L3 across iterations.
__global__ __launch_bounds__(256) void yolo_kernel(const float* __restrict__ in,
                                                   float* __restrict__ out) {
    __shared__ float4 smem[128 * ROWQ];      // 49152 B; aliased in-tile / out-stage
    float* const sin_ = (float*)smem;        // [85][128] floats (43520 B used)

    // XCD-chunked bijective swizzle (NWG % 8 == 0): consecutive tiles of the
    // same slab land on the same XCD/L2 -> contiguous ~2 MB read streams.
    const int bid  = (blockIdx.x & 7) * (NWG / 8) + (blockIdx.x >> 3);
    const int slab = bid / TPS;              // 0..47  (= b*3 + a)
    const int tile = bid - slab * TPS;       // 0..45
    // last tile overlaps the previous one (identical recompute, idempotent
    // identical stores) so no bounds checks are needed anywhere
    const int tp   = (tile == TPS - 1) ? (HW_ - 128) : (tile << 7);

    const int tid  = threadIdx.x;
    const int lane = tid & 63;
    const int wv   = tid >> 6;

    const float* sbase = in + (size_t)slab * (85 * (size_t)HW_) + tp;

    // ---- cooperative float4 load: 85 channel rows x 128 pos -> LDS ----
    // quad q: ch = q>>5, p4 = (q&31)*4; 85*32 = 2720 quads total, so the
    // final iteration runs with 160/256 threads active (static predicate).
    // Per wave-instr: 64 lanes x 16 B = 1 KB (2 channel rows x 512 B).
    // LDS write slot = tid%8 -> uniform across wave -> conflict-free.
#pragma unroll
    for (int it = 0; it < 11; ++it) {
        const int q = it * 256 + tid;
        if (q < 2720) {
            const int ch = q >> 5;
            const int p4 = (q & 31) << 2;
            const float4 d = *(const float4*)(sbase + (size_t)ch * HW_ + p4);
            *(float4*)(sin_ + (ch << 7) + p4) = d;
        }
    }
    __syncthreads();

    // ---- per-position compute: adjacent-lane pair per position ----
    const int pos  = tid >> 1;               // 0..127
    const int half = tid & 1;                // 40-class split
    const int p    = tp + pos;
    const int a    = slab % 3;

    const float aw3[3] = {1.5f, 2.375f, 5.0f};   // [12,19,40]/8
    const float ah3[3] = {2.0f, 4.5f, 3.5f};     // [16,36,28]/8
    const float invW = 1.0f / 76.0f;

    // box rows: pair lanes read the same address -> bank broadcast, free
    const float b0 = sin_[0 * 128 + pos];
    const float b1 = sin_[1 * 128 + pos];
    const float b2 = sin_[2 * 128 + pos];
    const float b3 = sin_[3 * 128 + pos];
    const float b4 = sin_[4 * 128 + pos];

    // class column: 40 x ds_read_b32, bank = pos%32, pair lanes differ in
    // address -> 2-way = free
    float v[40];
#pragma unroll
    for (int c = 0; c < 40; ++c) v[c] = sin_[(5 + 40 * half + c) * 128 + pos];

    // softmax over 80 classes (40/40 across the lane pair), 4 dep chains
    float m0 = v[0], m1 = v[1], m2 = v[2], m3 = v[3];
#pragma unroll
    for (int c = 4; c < 40; c += 4) {
        m0 = fmaxf(m0, v[c]);     m1 = fmaxf(m1, v[c + 1]);
        m2 = fmaxf(m2, v[c + 2]); m3 = fmaxf(m3, v[c + 3]);
    }
    float m = fmaxf(fmaxf(m0, m1), fmaxf(m2, m3));
    m = fmaxf(m, __shfl_xor(m, 1));
    float s0 = 0.f, s1 = 0.f, s2 = 0.f, s3 = 0.f;
#pragma unroll
    for (int c = 0; c < 40; c += 4) {
        v[c]     = __expf(v[c]     - m); s0 += v[c];
        v[c + 1] = __expf(v[c + 1] - m); s1 += v[c + 1];
        v[c + 2] = __expf(v[c + 2] - m); s2 += v[c + 2];
        v[c + 3] = __expf(v[c + 3] - m); s3 += v[c + 3];
    }
    float s = (s0 + s1) + (s2 + s3);
    s += __shfl_xor(s, 1);
    const float det   = sigmoidf_(b4);
    const float scale = det / s;

    // boxes: [P][4]; half-wave writes 512 B contiguous
    if (half == 0) {
        const int x = p % W_;
        const int y = p / W_;
        const float bx = (sigmoidf_(b0) + (float)x) * invW;
        const float by = (sigmoidf_(b1) + (float)y) * invW;
        const float bw = __expf(b2) * (aw3[a] * invW);
        const float bh = __expf(b3) * (ah3[a] * invW);
        nt_store4(make_float4(bx, by, bw, bh), (float4*)out + slab * HW_ + p);
    }

    // ---- conf: xor-swizzled LDS stage, then per-wave coalesced drain ----
    __syncthreads();   // all sin_ column reads done before aliasing overwrite
#pragma unroll
    for (int i = 0; i < 10; ++i) {
        const int k = half * 10 + i;
        smem[pos * ROWQ + (k ^ (pos & 7))] =
            make_float4(v[4 * i] * scale,     v[4 * i + 1] * scale,
                        v[4 * i + 2] * scale, v[4 * i + 3] * scale);
    }
    // wave w drains its own rows [w*32, w*32+32) -> same-wave DS ordering,
    // no extra barrier; 10 x 1 KB contiguous global stores per wave
    float4* conf4 = (float4*)out + NPOS + (size_t)(slab * HW_ + tp + wv * 32) * 20;
#pragma unroll
    for (int i = 0; i < 10; ++i) {
        const int f   = i * 64 + lane;       // 0..639
        const int pr  = f / 20;              // wave-local row 0..31
        const int kr  = f - pr * 20;         // 0..19
        const int row = wv * 32 + pr;
        nt_store4(smem[row * ROWQ + (kr ^ (row & 7))], conf4 + f);
    }
}

extern "C" void kernel_launch(void* const* d_in, const int* in_sizes, int n_in,
                              void* d_out, int out_size, void* d_ws, size_t ws_size,
                              hipStream_t stream) {
    const float* in = (const float*)d_in[0];
    float* out = (float*)d_out;
    yolo_kernel<<<NWG, 256, 0, stream>>>(in, out);
}

// Round 4
// 170.300 us; speedup vs baseline: 1.0072x; 1.0072x over previous
//
#include <hip/hip_runtime.h>

#define HW_   5776                 // 76*76
#define W_    76
#define NPOS  (16 * 3 * HW_)       // 277248 positions
#define NTILE (NPOS / 32)          // 8664 tiles of 32 positions (exact)
#define NBLK  512                  // blocks; % 8 == 0 -> simple XCD swizzle
#define NWAVE (NBLK * 4)           // 2048 persistent waves
#define ROWQ  21                   // odd float4 stride per LDS stage row

__device__ __forceinline__ float sigmoidf_(float x) {
    return 1.0f / (1.0f + __expf(-x));
}

// One tile = 32 positions owned by ONE wave; two lanes per position
// (half = lane>>5 handles 40 of the 80 classes). Input lives in registers.
struct TileReg {
    float b0, b1, b2, b3, b4;
    float v[40];
};

__device__ __forceinline__ void load_tile(const float* __restrict__ in,
                                          int P, int half, TileReg& T) {
    const int slab = P / HW_;              // b*3 + a
    const int p    = P - slab * HW_;
    const float* src = in + (size_t)slab * (85 * (size_t)HW_) + p;
    // box channels: both halves read the same address -> coalescer-merged
    T.b0 = src[0 * (size_t)HW_];
    T.b1 = src[1 * (size_t)HW_];
    T.b2 = src[2 * (size_t)HW_];
    T.b3 = src[3 * (size_t)HW_];
    T.b4 = src[4 * (size_t)HW_];
    // this half's 40 class channels: 2 x 128 B contiguous segments / instr
    const float* csrc = src + (size_t)(5 + half * 40) * HW_;
#pragma unroll
    for (int c = 0; c < 40; ++c) T.v[c] = csrc[(size_t)c * HW_];
}

__device__ __forceinline__ void process_tile(TileReg& T, int tile, int lane,
                                             int half, int pos, float4* ldsw,
                                             float* __restrict__ out) {
    const int P    = tile * 32 + pos;
    const int slab = P / HW_;
    const int p    = P - slab * HW_;
    const int a    = slab % 3;

    const float aw3[3] = {1.5f, 2.375f, 5.0f};   // [12,19,40]/8
    const float ah3[3] = {2.0f, 4.5f, 3.5f};     // [16,36,28]/8
    const float invW = 1.0f / 76.0f;

    // softmax over 80 classes (40/40 across the half pair), 4 dep chains
    float m0 = T.v[0], m1 = T.v[1], m2 = T.v[2], m3 = T.v[3];
#pragma unroll
    for (int c = 4; c < 40; c += 4) {
        m0 = fmaxf(m0, T.v[c]);     m1 = fmaxf(m1, T.v[c + 1]);
        m2 = fmaxf(m2, T.v[c + 2]); m3 = fmaxf(m3, T.v[c + 3]);
    }
    float m = fmaxf(fmaxf(m0, m1), fmaxf(m2, m3));
    m = fmaxf(m, __shfl_xor(m, 32));
    float s0 = 0.f, s1 = 0.f, s2 = 0.f, s3 = 0.f;
#pragma unroll
    for (int c = 0; c < 40; c += 4) {
        T.v[c]     = __expf(T.v[c]     - m); s0 += T.v[c];
        T.v[c + 1] = __expf(T.v[c + 1] - m); s1 += T.v[c + 1];
        T.v[c + 2] = __expf(T.v[c + 2] - m); s2 += T.v[c + 2];
        T.v[c + 3] = __expf(T.v[c + 3] - m); s3 += T.v[c + 3];
    }
    float s = (s0 + s1) + (s2 + s3);
    s += __shfl_xor(s, 32);
    const float det   = sigmoidf_(T.b4);
    const float scale = det / s;

    // boxes: [P][4]; half-wave writes 512 B contiguous
    if (half == 0) {
        const int x = p % W_;
        const int y = p / W_;
        const float bx = (sigmoidf_(T.b0) + (float)x) * invW;
        const float by = (sigmoidf_(T.b1) + (float)y) * invW;
        const float bw = __expf(T.b2) * (aw3[a] * invW);
        const float bh = __expf(T.b3) * (ah3[a] * invW);
        ((float4*)out)[P] = make_float4(bx, by, bw, bh);
    }

    // conf: wave-private LDS stage (odd-stride rows -> even bank-group
    // spread), then fully-coalesced drain. Same-wave in-order DS pipe =>
    // no barrier; also safe across tile iterations for the same reason.
#pragma unroll
    for (int i = 0; i < 10; ++i) {
        const int k = half * 10 + i;
        ldsw[pos * ROWQ + k] = make_float4(T.v[4 * i]     * scale,
                                           T.v[4 * i + 1] * scale,
                                           T.v[4 * i + 2] * scale,
                                           T.v[4 * i + 3] * scale);
    }
    float4* conf4 = (float4*)out + NPOS + (size_t)(tile * 32) * 20;
#pragma unroll
    for (int i = 0; i < 10; ++i) {
        const int f  = i * 64 + lane;        // 0..639
        const int pr = f / 20;               // row 0..31
        const int kr = f - pr * 20;          // 0..19
        conf4[f] = ldsw[pr * ROWQ + kr];     // 10 x 1 KB contiguous stores
    }
}

// Persistent grid-stride waves with a ping-pong register pipeline: loads for
// tile t+NWAVE are issued BEFORE the compute of tile t, so each wave keeps
// ~11 KB of loads in flight continuously instead of in bursts. No
// __syncthreads anywhere. This targets the one invariant of rounds 0-3
// (all 59 us): bursty vmem issue capping average outstanding bytes.
__global__ __launch_bounds__(256) void yolo_kernel(const float* __restrict__ in,
                                                   float* __restrict__ out) {
    __shared__ float4 lds[4][32 * ROWQ];     // 43008 B / block, wave-private rows

    const int tid  = threadIdx.x;
    const int lane = tid & 63;
    const int wv   = tid >> 6;
    const int half = lane >> 5;
    const int pos  = lane & 31;

    // XCD swizzle (NBLK % 8 == 0): each XCD's 64 blocks cover a contiguous
    // 256-tile span per grid-stride round -> neighbor tiles sharing split
    // 128 B lines (channel stride 23104 B == 64 mod 128) stay in one L2.
    const int bid = (blockIdx.x & 7) * (NBLK / 8) + (blockIdx.x >> 3);
    const int g   = bid * 4 + wv;            // 0..2047, g < NTILE always
    float4* ldsw  = lds[wv];

    TileReg A, B;
    int tA = g;
    load_tile(in, tA * 32 + pos, half, A);
    for (;;) {
        const int tB = tA + NWAVE;
        if (tB < NTILE) {
            load_tile(in, tB * 32 + pos, half, B);       // in flight over A
            process_tile(A, tA, lane, half, pos, ldsw, out);
            const int tA2 = tB + NWAVE;
            if (tA2 < NTILE) {
                load_tile(in, tA2 * 32 + pos, half, A);  // in flight over B
                process_tile(B, tB, lane, half, pos, ldsw, out);
                tA = tA2;
                continue;
            }
            process_tile(B, tB, lane, half, pos, ldsw, out);
            break;
        }
        process_tile(A, tA, lane, half, pos, ldsw, out);
        break;
    }
}

extern "C" void kernel_launch(void* const* d_in, const int* in_sizes, int n_in,
                              void* d_out, int out_size, void* d_ws, size_t ws_size,
                              hipStream_t stream) {
    const float* in = (const float*)d_in[0];
    float* out = (float*)d_out;
    yolo_kernel<<<NBLK, 256, 0, stream>>>(in, out);
}